// Round 5
// baseline (273.700 us; speedup 1.0000x reference)
//
#include <hip/hip_runtime.h>

// Problem constants: B=4, M=512, L=31, S=2, W=M+L-1=542
#define CB 4
#define CM 512
#define CL 31
#define CW 542
#define SLAB  (CM * CL)      // 15872 floats of H per (b,m) slab
#define SLAB4 (SLAB / 4)     // 3968 float4 (= 15.5 * 256)
#define NBM   (CB * CM)      // 2048 slabs
#define CPAD  543            // ysum copy stride (543 mod 32 = 31 -> bank-spread)

typedef float f32x4 __attribute__((ext_vector_type(4)));

// X[b,m,n,l] = H[b,m,n,l] * (Y[b,m,n+l,0] + Y[b,m,n+l,1]); out = X / max(X)
//
// Work split (R5): pass 1 computes X once, stores it UNNORMALIZED to out
// (plain stores -> write-allocate into L3; H's clean lines are the eviction
// victims) and records per-block maxima. Pass 2 is a pure in-place scale of
// out -- no Y, no LDS, no index math; reads hit the L3-resident X lines and
// stores re-dirty the same lines (no forced HBM round-trip in the timed
// region). Bit-exact vs the old scheme: (h*ys) stored f32, then *inv.
//
// R2 lesson: no grid.sync fusion (300us). R4 lesson: no extra memset
// dispatch (blockmax array handoff, fully written before read).
//
// ysum staged as FOUR replicated copies at stride 543 (543 mod 32 = 31);
// lane uses copy (tid>>3)&3 -> stride-4 gather is exactly 2-way (= free).
// Index math: f = 4*tid + 1024*k; 1024 = 33*31 + 1 -> l advances +1/iter,
// carried incrementally; no int division in the loop.

__device__ __forceinline__ void stage_ysum(const float* __restrict__ Y, int bm,
                                           float* __restrict__ ys) {
    const float2* y2 = (const float2*)(Y + (size_t)bm * (CW * 2));
    for (int j = threadIdx.x; j < CW; j += 256) {
        float2 v = y2[j];
        float s = v.x + v.y;
        ys[j]            = s;
        ys[j + CPAD]     = s;
        ys[j + 2 * CPAD] = s;
        ys[j + 3 * CPAD] = s;
    }
}

struct IdxState {
    int l0;   // f % 31 for the quad base
    int i0;   // n0 + l0 (ysum index of the quad's first element)
};

__device__ __forceinline__ IdxState idx_init(int tid) {
    unsigned f = 4u * (unsigned)tid;
    unsigned n = f / 31u;            // one division, outside the loop
    IdxState s;
    s.l0 = (int)(f - n * 31u);
    s.i0 = (int)n + s.l0;
    return s;
}

__device__ __forceinline__ void idx_quad(const IdxState& s,
                                         int& i0, int& i1, int& i2, int& i3) {
    // element j wraps iff l0 >= 31-j (at most one wrap per quad, L=31>4)
    i0 = s.i0;
    i1 = s.i0 + ((s.l0 >= 30) ? 1 - 30 : 1);
    i2 = s.i0 + ((s.l0 >= 29) ? 2 - 30 : 2);
    i3 = s.i0 + ((s.l0 >= 28) ? 3 - 30 : 3);
}

__device__ __forceinline__ void idx_step(IdxState& s) {
    // f += 1024 -> l0 += 1 (mod 31); i0 += 34 (or +4 on wrap)
    bool w = (s.l0 == 30);
    s.i0 += w ? 4 : 34;
    s.l0  = w ? 0 : (s.l0 + 1);
}

__device__ __forceinline__ f32x4 quad_x(const f32x4& h, const float* __restrict__ ys,
                                        const IdxState& st) {
    int i0, i1, i2, i3;
    idx_quad(st, i0, i1, i2, i3);
    f32x4 x = { h[0] * ys[i0], h[1] * ys[i1], h[2] * ys[i2], h[3] * ys[i3] };
    return x;
}

__device__ __forceinline__ float quad_fold(const f32x4& x) {
    return fmaxf(fmaxf(x[0], x[1]), fmaxf(x[2], x[3]));
}

// ---------- pass 1: X = H*ysum -> out (unnormalized), per-block max ----------
__global__ __launch_bounds__(256, 8) void cassi_xmax(
    const float* __restrict__ Y,
    const float* __restrict__ H,
    float* __restrict__ blockmax,
    float* __restrict__ out)
{
    __shared__ float ysum[4 * CPAD];
    __shared__ float smax[4];
    const int bm  = blockIdx.x;
    const int tid = threadIdx.x;

    const f32x4* h4 = (const f32x4*)(H + (size_t)bm * SLAB);
    // prefetch 2 quads: cold-HBM latency overlaps the staging barrier
    f32x4 h0 = h4[tid];
    f32x4 h1 = h4[tid + 256];

    stage_ysum(Y, bm, ysum);
    __syncthreads();

    const float* ys = ysum + ((tid >> 3) & 3) * CPAD;
    f32x4* o4 = (f32x4*)(out + (size_t)bm * SLAB);
    IdxState st = idx_init(tid);
    float mx = 0.0f;   // all X >= 0 (H,Y uniform [0,1))

    {
        f32x4 x = quad_x(h0, ys, st);
        o4[tid] = x;                       // plain store: allocate in L3
        mx = fmaxf(mx, quad_fold(x));
        idx_step(st);
    }
    {
        f32x4 x = quad_x(h1, ys, st);
        o4[tid + 256] = x;
        mx = fmaxf(mx, quad_fold(x));
        idx_step(st);
    }

#pragma unroll 4
    for (int k = 2; k < 15; ++k) {
        f32x4 h = h4[tid + (k << 8)];
        f32x4 x = quad_x(h, ys, st);
        o4[tid + (k << 8)] = x;
        mx = fmaxf(mx, quad_fold(x));
        idx_step(st);
    }
    if (tid < 128) {   // tail half-pass: SLAB4 = 15.5 * 256
        f32x4 h = h4[tid + 15 * 256];
        f32x4 x = quad_x(h, ys, st);
        o4[tid + 15 * 256] = x;
        mx = fmaxf(mx, quad_fold(x));
    }

#pragma unroll
    for (int off = 32; off > 0; off >>= 1)
        mx = fmaxf(mx, __shfl_down(mx, off, 64));
    if ((tid & 63) == 0) smax[tid >> 6] = mx;
    __syncthreads();
    if (tid == 0)
        blockmax[bm] = fmaxf(fmaxf(smax[0], smax[1]), fmaxf(smax[2], smax[3]));
}

// ---------- pass 2: out *= 1/max (pure in-place scale, L3-resident) ----------
__global__ __launch_bounds__(256, 8) void cassi_scale(
    const float* __restrict__ blockmax,
    float* __restrict__ out)
{
    __shared__ float smax[4];
    const int bm  = blockIdx.x;
    const int tid = threadIdx.x;

    // global max = reduce of 2048 per-block maxima (2 float4 loads/thread)
    const f32x4* b4 = (const f32x4*)blockmax;   // 512 quads
    f32x4 a = b4[tid];
    f32x4 b = b4[tid + 256];
    float m = fmaxf(fmaxf(fmaxf(a[0], a[1]), fmaxf(a[2], a[3])),
                    fmaxf(fmaxf(b[0], b[1]), fmaxf(b[2], b[3])));
#pragma unroll
    for (int off = 32; off > 0; off >>= 1)
        m = fmaxf(m, __shfl_down(m, off, 64));
    if ((tid & 63) == 0) smax[tid >> 6] = m;
    __syncthreads();
    const float inv = 1.0f / fmaxf(fmaxf(smax[0], smax[1]), fmaxf(smax[2], smax[3]));

    f32x4* o4 = (f32x4*)(out + (size_t)bm * SLAB);   // same slab this block wrote
#pragma unroll 5
    for (int k = 0; k < 15; ++k) {
        f32x4 v = o4[tid + (k << 8)];
        v[0] *= inv; v[1] *= inv; v[2] *= inv; v[3] *= inv;
        o4[tid + (k << 8)] = v;    // plain store: line stays dirty in L3
    }
    if (tid < 128) {
        f32x4 v = o4[tid + 15 * 256];
        v[0] *= inv; v[1] *= inv; v[2] *= inv; v[3] *= inv;
        o4[tid + 15 * 256] = v;
    }
}

extern "C" void kernel_launch(void* const* d_in, const int* in_sizes, int n_in,
                              void* d_out, int out_size, void* d_ws, size_t ws_size,
                              hipStream_t stream)
{
    (void)in_sizes; (void)n_in; (void)out_size; (void)ws_size;
    const float* Y = (const float*)d_in[0];   // (B, M, W, S)
    const float* H = (const float*)d_in[1];   // (B, M, M, L)
    float* out = (float*)d_out;               // (B, M, M, L)
    float* blockmax = (float*)d_ws;           // 2048 floats; fully written before read

    cassi_xmax<<<NBM, 256, 0, stream>>>(Y, H, blockmax, out);
    cassi_scale<<<NBM, 256, 0, stream>>>(blockmax, out);
}

// Round 6
// 251.203 us; speedup vs baseline: 1.0896x; 1.0896x over previous
//
#include <hip/hip_runtime.h>

// Problem constants: B=4, M=512, L=31, S=2, W=M+L-1=542
#define CB 4
#define CM 512
#define CL 31
#define CW 542
#define SLAB  (CM * CL)      // 15872 floats of H per (b,m) slab
#define SLAB4 (SLAB / 4)     // 3968 float4 (= 15.5 * 256)
#define NBM   (CB * CM)      // 2048 slabs
#define CPAD  543            // ysum copy stride (543 mod 32 = 31 -> bank-spread)

typedef float f32x4 __attribute__((ext_vector_type(4)));

// X[b,m,n,l] = H[b,m,n,l] * (Y[b,m,n+l,0] + Y[b,m,n+l,1]); out = X / max(X)
// Two kernels (max, then scale); one block per (b,m) slab, 256 threads.
//
// Structure lessons (measured):
//  R2: cooperative grid.sync fusion     -> 300us kernel. Never again.
//  R4: scalar atomicMax + memset node   -> +5us (extra dispatch drain).
//  R5: store-X-then-rescale             -> pass1 83us @30% BW: plain stores
//      write-allocate, evict H from L3, and X writes go to HBM anyway.
//  R3 (this structure): 252.7us total. Pass1 plain-loads H (fills/keeps L3);
//      pass2 re-reads H from L3 and nt-stores out (no write-allocate, H stays
//      resident across passes AND bench iterations).
//
// ysum staged as FOUR replicated copies at stride 543 (543 mod 32 = 31);
// lane uses copy (tid>>3)&3 -> stride-4 gather is exactly 2-way (= free).
// Index math: f = 4*tid + 1024*k; 1024 = 33*31 + 1 -> l advances +1/iter,
// carried incrementally; no int division in the loop.
// grid == 8 blocks/CU * 256 CU exactly -> one block-wave; first 2 H quads are
// prefetched across the staging barrier to hide the prologue.

__device__ __forceinline__ void stage_ysum(const float* __restrict__ Y, int bm,
                                           float* __restrict__ ys) {
    const float2* y2 = (const float2*)(Y + (size_t)bm * (CW * 2));
    for (int j = threadIdx.x; j < CW; j += 256) {
        float2 v = y2[j];
        float s = v.x + v.y;
        ys[j]            = s;
        ys[j + CPAD]     = s;
        ys[j + 2 * CPAD] = s;
        ys[j + 3 * CPAD] = s;
    }
}

struct IdxState {
    int l0;   // f % 31 for the quad base
    int i0;   // n0 + l0 (ysum index of the quad's first element)
};

__device__ __forceinline__ IdxState idx_init(int tid) {
    unsigned f = 4u * (unsigned)tid;
    unsigned n = f / 31u;            // one division, outside the loop
    IdxState s;
    s.l0 = (int)(f - n * 31u);
    s.i0 = (int)n + s.l0;
    return s;
}

__device__ __forceinline__ void idx_quad(const IdxState& s,
                                         int& i0, int& i1, int& i2, int& i3) {
    // element j wraps iff l0 >= 31-j (at most one wrap per quad, L=31>4)
    i0 = s.i0;
    i1 = s.i0 + ((s.l0 >= 30) ? 1 - 30 : 1);
    i2 = s.i0 + ((s.l0 >= 29) ? 2 - 30 : 2);
    i3 = s.i0 + ((s.l0 >= 28) ? 3 - 30 : 3);
}

__device__ __forceinline__ void idx_step(IdxState& s) {
    // f += 1024 -> l0 += 1 (mod 31); i0 += 34 (or +4 on wrap)
    bool w = (s.l0 == 30);
    s.i0 += w ? 4 : 34;
    s.l0  = w ? 0 : (s.l0 + 1);
}

__device__ __forceinline__ float quad_max(const f32x4& h, const float* __restrict__ ys,
                                          const IdxState& st) {
    int i0, i1, i2, i3;
    idx_quad(st, i0, i1, i2, i3);
    return fmaxf(fmaxf(h[0] * ys[i0], h[1] * ys[i1]),
                 fmaxf(h[2] * ys[i2], h[3] * ys[i3]));
}

__global__ __launch_bounds__(256, 8) void cassi_max_k(
    const float* __restrict__ Y,
    const float* __restrict__ H,
    float* __restrict__ blockmax)
{
    __shared__ float ysum[4 * CPAD];
    __shared__ float smax[4];
    const int bm  = blockIdx.x;
    const int tid = threadIdx.x;

    const f32x4* h4 = (const f32x4*)(H + (size_t)bm * SLAB);
    // prefetch first two quads: HBM latency overlaps the staging barrier
    f32x4 h0 = h4[tid];
    f32x4 h1 = h4[tid + 256];

    stage_ysum(Y, bm, ysum);
    __syncthreads();

    const float* ys = ysum + ((tid >> 3) & 3) * CPAD;
    IdxState st = idx_init(tid);
    float mx = 0.0f;   // all X >= 0 (H,Y uniform [0,1))

    mx = fmaxf(mx, quad_max(h0, ys, st)); idx_step(st);
    mx = fmaxf(mx, quad_max(h1, ys, st)); idx_step(st);

#pragma unroll 5
    for (int k = 2; k < 15; ++k) {
        f32x4 h = h4[tid + (k << 8)];
        mx = fmaxf(mx, quad_max(h, ys, st));
        idx_step(st);
    }
    if (tid < 128) {   // tail half-pass: SLAB4 = 15.5 * 256
        f32x4 h = h4[tid + 15 * 256];
        mx = fmaxf(mx, quad_max(h, ys, st));
    }

#pragma unroll
    for (int off = 32; off > 0; off >>= 1)
        mx = fmaxf(mx, __shfl_down(mx, off, 64));
    if ((tid & 63) == 0) smax[tid >> 6] = mx;
    __syncthreads();
    if (tid == 0)
        blockmax[bm] = fmaxf(fmaxf(smax[0], smax[1]), fmaxf(smax[2], smax[3]));
}

__global__ __launch_bounds__(256, 8) void cassi_out_k(
    const float* __restrict__ Y,
    const float* __restrict__ H,
    const float* __restrict__ blockmax,
    float* __restrict__ out)
{
    __shared__ float ysum[4 * CPAD];
    __shared__ float smax[4];
    const int bm  = blockIdx.x;
    const int tid = threadIdx.x;

    const f32x4* h4 = (const f32x4*)(H + (size_t)bm * SLAB);
    f32x4 h0 = h4[tid];          // prefetch across the staging prologue
    f32x4 h1 = h4[tid + 256];

    stage_ysum(Y, bm, ysum);

    // global max = reduce of 2048 per-block maxima (2 float4 loads/thread,
    // L2-broadcast; cheaper than 8 scalar loads -- carried from R5 pass 2)
    const f32x4* b4 = (const f32x4*)blockmax;   // 512 quads
    f32x4 a = b4[tid & 255];
    f32x4 b = b4[(tid & 255) + 256];
    float m = fmaxf(fmaxf(fmaxf(a[0], a[1]), fmaxf(a[2], a[3])),
                    fmaxf(fmaxf(b[0], b[1]), fmaxf(b[2], b[3])));
#pragma unroll
    for (int off = 32; off > 0; off >>= 1)
        m = fmaxf(m, __shfl_down(m, off, 64));
    if ((tid & 63) == 0) smax[tid >> 6] = m;
    __syncthreads();   // covers ysum and smax stores
    const float inv = 1.0f / fmaxf(fmaxf(smax[0], smax[1]), fmaxf(smax[2], smax[3]));

    const float* ys = ysum + ((tid >> 3) & 3) * CPAD;
    f32x4* o4 = (f32x4*)(out + (size_t)bm * SLAB);
    IdxState st = idx_init(tid);

    // nontemporal stores: out is never re-read; don't let write-allocate
    // evict the L3-resident H (H + out = 260 MB > 256 MB L3). H loads stay
    // plain (those are the lines we want kept). Measured: R5's plain-store
    // variant ran pass 1 at 30% BW -- this discipline is the difference.
    {
        int i0, i1, i2, i3;
        idx_quad(st, i0, i1, i2, i3);
        f32x4 o = { h0[0] * ys[i0] * inv, h0[1] * ys[i1] * inv,
                    h0[2] * ys[i2] * inv, h0[3] * ys[i3] * inv };
        __builtin_nontemporal_store(o, &o4[tid]);
        idx_step(st);
    }
    {
        int i0, i1, i2, i3;
        idx_quad(st, i0, i1, i2, i3);
        f32x4 o = { h1[0] * ys[i0] * inv, h1[1] * ys[i1] * inv,
                    h1[2] * ys[i2] * inv, h1[3] * ys[i3] * inv };
        __builtin_nontemporal_store(o, &o4[tid + 256]);
        idx_step(st);
    }

#pragma unroll 5
    for (int k = 2; k < 15; ++k) {
        f32x4 h = h4[tid + (k << 8)];
        int i0, i1, i2, i3;
        idx_quad(st, i0, i1, i2, i3);
        f32x4 o = { h[0] * ys[i0] * inv, h[1] * ys[i1] * inv,
                    h[2] * ys[i2] * inv, h[3] * ys[i3] * inv };
        __builtin_nontemporal_store(o, &o4[tid + (k << 8)]);
        idx_step(st);
    }
    if (tid < 128) {
        f32x4 h = h4[tid + 15 * 256];
        int i0, i1, i2, i3;
        idx_quad(st, i0, i1, i2, i3);
        f32x4 o = { h[0] * ys[i0] * inv, h[1] * ys[i1] * inv,
                    h[2] * ys[i2] * inv, h[3] * ys[i3] * inv };
        __builtin_nontemporal_store(o, &o4[tid + 15 * 256]);
    }
}

extern "C" void kernel_launch(void* const* d_in, const int* in_sizes, int n_in,
                              void* d_out, int out_size, void* d_ws, size_t ws_size,
                              hipStream_t stream)
{
    (void)in_sizes; (void)n_in; (void)out_size; (void)ws_size;
    const float* Y = (const float*)d_in[0];   // (B, M, W, S)
    const float* H = (const float*)d_in[1];   // (B, M, M, L)
    float* out = (float*)d_out;               // (B, M, M, L)
    float* blockmax = (float*)d_ws;           // 2048 floats; fully written before read

    cassi_max_k<<<NBM, 256, 0, stream>>>(Y, H, blockmax);
    cassi_out_k<<<NBM, 256, 0, stream>>>(Y, H, blockmax, out);
}